// Round 1
// baseline (494.236 us; speedup 1.0000x reference)
//
#include <hip/hip_runtime.h>
#include <math.h>

#define SCALE_C 0.08838834764831845f  // 1/sqrt(128)

// align_corners bilinear coefficients for 32 -> 64 (src = t*31/63)
__device__ __forceinline__ void interp_coef32(int t, int& i0, int& i1, float& w) {
    float s = (float)(t * 31) / 63.0f;
    i0 = (int)floorf(s);
    if (i0 > 31) i0 = 31;
    i1 = i0 + 1;
    if (i1 > 31) i1 = 31;
    w = s - (float)i0;
}

// ---------------------------------------------------------------------------
// corr_c: [b,1024,1024] = f0c^T f1c / sqrt(128). 64x64 tile per block.
// ---------------------------------------------------------------------------
__global__ __launch_bounds__(256) void k_corr_c(const float* __restrict__ f0c,
                                                const float* __restrict__ f1c,
                                                float* __restrict__ ws) {
    __shared__ float As[16][64];
    __shared__ float Bs[16][64];
    const int b = blockIdx.z;
    const int m0 = blockIdx.y * 64, n0 = blockIdx.x * 64;
    const float* A  = f0c + (long long)b * 131072;  // [128][1024]
    const float* Bp = f1c + (long long)b * 131072;
    const int tid = threadIdx.x;
    const int tx = tid & 15, ty = tid >> 4;
    const int lk = tid >> 4;
    const int lc = (tid & 15) * 4;
    float acc[4][4] = {{0.f}};
    for (int k0 = 0; k0 < 128; k0 += 16) {
        *(float4*)&As[lk][lc] = *(const float4*)&A[(k0 + lk) * 1024 + m0 + lc];
        *(float4*)&Bs[lk][lc] = *(const float4*)&Bp[(k0 + lk) * 1024 + n0 + lc];
        __syncthreads();
#pragma unroll
        for (int kk = 0; kk < 16; ++kk) {
            float4 a4 = *(float4*)&As[kk][ty * 4];
            float4 b4 = *(float4*)&Bs[kk][tx * 4];
            float av[4] = {a4.x, a4.y, a4.z, a4.w};
            float bv[4] = {b4.x, b4.y, b4.z, b4.w};
#pragma unroll
            for (int i = 0; i < 4; ++i)
#pragma unroll
                for (int j = 0; j < 4; ++j)
                    acc[i][j] = fmaf(av[i], bv[j], acc[i][j]);
        }
        __syncthreads();
    }
#pragma unroll
    for (int i = 0; i < 4; ++i) {
        float4 w4 = make_float4(acc[i][0] * SCALE_C, acc[i][1] * SCALE_C,
                                acc[i][2] * SCALE_C, acc[i][3] * SCALE_C);
        *(float4*)&ws[(long long)b * 1048576 + (long long)(m0 + ty * 4 + i) * 1024 + n0 + tx * 4] = w4;
    }
}

// ---------------------------------------------------------------------------
// fused: c[b,y0,x0,y1,x1] = 0.5*(up4d(corr_c) + corr_f). One block per
// (b, y0, y1): computes the 64(x0) x 64(x1) tile, writes c and c_flip.
// ---------------------------------------------------------------------------
__global__ __launch_bounds__(256) void k_fused(const float* __restrict__ f0f,
                                               const float* __restrict__ f1f,
                                               const float* __restrict__ cws,
                                               float* __restrict__ c_out,
                                               float* __restrict__ cf_out) {
    __shared__ float As[16][64];
    __shared__ float Bs[16][64];
    __shared__ float tmp[32][33];
    const int b = blockIdx.z, y0 = blockIdx.y, y1 = blockIdx.x;
    const int tid = threadIdx.x;
    const int tx = tid & 15, ty = tid >> 4;
    const float* A  = f0f + (long long)b * 524288 + y0 * 64;  // [k][4096] + x0
    const float* Bp = f1f + (long long)b * 524288 + y1 * 64;

    // stage y-interpolated coarse correlation (32x32 over (xc0, xc1))
    int iy0a, iy0b; float wy0; interp_coef32(y0, iy0a, iy0b, wy0);
    int iy1a, iy1b; float wy1; interp_coef32(y1, iy1a, iy1b, wy1);
    const float* Cc = cws + (long long)b * 1048576;
    for (int r = tid; r < 1024; r += 256) {
        int i = r >> 5, j = r & 31;
        const float* ra = Cc + (long long)(iy0a * 32 + i) * 1024;
        const float* rb = Cc + (long long)(iy0b * 32 + i) * 1024;
        float va = ra[iy1a * 32 + j] * (1.f - wy1) + ra[iy1b * 32 + j] * wy1;
        float vb = rb[iy1a * 32 + j] * (1.f - wy1) + rb[iy1b * 32 + j] * wy1;
        tmp[i][j] = va * (1.f - wy0) + vb * wy0;
    }

    float acc[4][4] = {{0.f}};
    const int lk = tid >> 4;
    const int lc = (tid & 15) * 4;
    for (int k0 = 0; k0 < 128; k0 += 16) {
        *(float4*)&As[lk][lc] = *(const float4*)&A[(long long)(k0 + lk) * 4096 + lc];
        *(float4*)&Bs[lk][lc] = *(const float4*)&Bp[(long long)(k0 + lk) * 4096 + lc];
        __syncthreads();
#pragma unroll
        for (int kk = 0; kk < 16; ++kk) {
            float4 a4 = *(float4*)&As[kk][ty * 4];
            float4 b4 = *(float4*)&Bs[kk][tx * 4];
            float av[4] = {a4.x, a4.y, a4.z, a4.w};
            float bv[4] = {b4.x, b4.y, b4.z, b4.w};
#pragma unroll
            for (int i = 0; i < 4; ++i)
#pragma unroll
                for (int j = 0; j < 4; ++j)
                    acc[i][j] = fmaf(av[i], bv[j], acc[i][j]);
        }
        __syncthreads();
    }

    // x-dim interpolation coefficients for this thread's 4x4 micro-tile
    int ix0a[4], ix0b[4]; float wx0[4];
    int ix1a[4], ix1b[4]; float wx1[4];
#pragma unroll
    for (int i = 0; i < 4; ++i) interp_coef32(ty * 4 + i, ix0a[i], ix0b[i], wx0[i]);
#pragma unroll
    for (int j = 0; j < 4; ++j) interp_coef32(tx * 4 + j, ix1a[j], ix1b[j], wx1[j]);

    float val[4][4];
#pragma unroll
    for (int i = 0; i < 4; ++i) {
#pragma unroll
        for (int j = 0; j < 4; ++j) {
            float taa = tmp[ix0a[i]][ix1a[j]], tab = tmp[ix0a[i]][ix1b[j]];
            float tba = tmp[ix0b[i]][ix1a[j]], tbb = tmp[ix0b[i]][ix1b[j]];
            float ta = taa * (1.f - wx1[j]) + tab * wx1[j];
            float tb = tba * (1.f - wx1[j]) + tbb * wx1[j];
            float up = ta * (1.f - wx0[i]) + tb * wx0[i];
            val[i][j] = (acc[i][j] * SCALE_C + up) * 0.5f;
        }
    }

    const long long cbase = ((long long)b << 24) + (long long)(y0 * 64) * 4096 + y1 * 64;
#pragma unroll
    for (int i = 0; i < 4; ++i) {
        *(float4*)&c_out[cbase + (long long)(ty * 4 + i) * 4096 + tx * 4] =
            make_float4(val[i][0], val[i][1], val[i][2], val[i][3]);
    }
    const long long fbase = ((long long)b << 24) + (long long)(y1 * 64) * 4096 + y0 * 64;
#pragma unroll
    for (int j = 0; j < 4; ++j) {
        *(float4*)&cf_out[fbase + (long long)(tx * 4 + j) * 4096 + ty * 4] =
            make_float4(val[0][j], val[1][j], val[2][j], val[3][j]);
    }
}

// ---------------------------------------------------------------------------
// trans_features = stack([f0f, f1f], axis=1)  (float4 copy)
// ---------------------------------------------------------------------------
__global__ void k_copy_trans(const float* __restrict__ f0f, const float* __restrict__ f1f,
                             float* __restrict__ out1) {
    int idx = blockIdx.x * 256 + threadIdx.x;  // 524288 float4s total
    int bv = idx >> 17;                        // 131072 float4 per (b,v)
    int r = idx & 131071;
    int b = bv >> 1, v = bv & 1;
    const float4* src = (const float4*)(v ? f1f : f0f) + (long long)b * 131072 + r;
    ((float4*)out1)[idx] = *src;
}

// ---------------------------------------------------------------------------
// trans_features_coarse: bilinear 32->64 (align_corners) of stacked feat_c
// ---------------------------------------------------------------------------
__global__ void k_coarse(const float* __restrict__ f0c, const float* __restrict__ f1c,
                         float* __restrict__ out2) {
    int idx = blockIdx.x * 256 + threadIdx.x;  // 2,097,152 elements
    int x = idx & 63, y = (idx >> 6) & 63, ch = (idx >> 12) & 127;
    int v = (idx >> 19) & 1, b = idx >> 20;
    int iy0, iy1; float wy; interp_coef32(y, iy0, iy1, wy);
    int ix0, ix1; float wx; interp_coef32(x, ix0, ix1, wx);
    const float* src = (v ? f1c : f0c) + (long long)(b * 128 + ch) * 1024;
    float a  = src[iy0 * 32 + ix0] * (1.f - wy) + src[iy1 * 32 + ix0] * wy;
    float c2 = src[iy0 * 32 + ix1] * (1.f - wy) + src[iy1 * 32 + ix1] * wy;
    out2[idx] = a * (1.f - wx) + c2 * wx;
}

// ---------------------------------------------------------------------------
// soft-argmax over one 4096-float row per block; writes the 2 flow channels.
// row r of `cmat` corresponds to target pixel p = r&4095 of batch b = r>>12;
// channel coordinate of entry q is (qy = q>>6, qx = q&63).
// ---------------------------------------------------------------------------
__global__ __launch_bounds__(256) void k_softargmax(const float* __restrict__ cmat,
                                                    float* __restrict__ flow_out) {
    const int tid = threadIdx.x;
    const float4* src = (const float4*)cmat + (long long)blockIdx.x * 1024;
    float4 r0 = src[tid];
    float4 r1 = src[tid + 256];
    float4 r2 = src[tid + 512];
    float4 r3 = src[tid + 768];

    float m = fmaxf(fmaxf(fmaxf(r0.x, r0.y), fmaxf(r0.z, r0.w)),
                    fmaxf(fmaxf(r1.x, r1.y), fmaxf(r1.z, r1.w)));
    m = fmaxf(m, fmaxf(fmaxf(r2.x, r2.y), fmaxf(r2.z, r2.w)));
    m = fmaxf(m, fmaxf(fmaxf(r3.x, r3.y), fmaxf(r3.z, r3.w)));

    __shared__ float red[16];
    const int lane = tid & 63, wave = tid >> 6;
#pragma unroll
    for (int off = 32; off > 0; off >>= 1) m = fmaxf(m, __shfl_xor(m, off, 64));
    if (lane == 0) red[wave] = m;
    __syncthreads();
    m = fmaxf(fmaxf(red[0], red[1]), fmaxf(red[2], red[3]));

    float l = 0.f, sx = 0.f, sy = 0.f;
    const float step = 2.f / 63.f;
#pragma unroll
    for (int s = 0; s < 4; ++s) {
        float4 r = (s == 0) ? r0 : (s == 1) ? r1 : (s == 2) ? r2 : r3;
        int f = tid + s * 256;                 // float4 index within row
        float yn = -1.f + (float)(f >> 4) * step;
        float xb = (float)((f & 15) * 4);
        float e0 = expf((r.x - m) * 50.f);
        float e1 = expf((r.y - m) * 50.f);
        float e2 = expf((r.z - m) * 50.f);
        float e3 = expf((r.w - m) * 50.f);
        float es = e0 + e1 + e2 + e3;
        l += es;
        sy += es * yn;
        sx += e0 * (-1.f + xb * step) + e1 * (-1.f + (xb + 1.f) * step)
            + e2 * (-1.f + (xb + 2.f) * step) + e3 * (-1.f + (xb + 3.f) * step);
    }
#pragma unroll
    for (int off = 32; off > 0; off >>= 1) {
        l  += __shfl_xor(l, off, 64);
        sx += __shfl_xor(sx, off, 64);
        sy += __shfl_xor(sy, off, 64);
    }
    if (lane == 0) { red[4 + wave] = l; red[8 + wave] = sx; red[12 + wave] = sy; }
    __syncthreads();
    if (tid == 0) {
        float L  = red[4] + red[5] + red[6] + red[7];
        float SX = red[8] + red[9] + red[10] + red[11];
        float SY = red[12] + red[13] + red[14] + red[15];
        float gx = SX / L, gy = SY / L;
        float mx = (gx + 1.f) * 31.5f;
        float my = (gy + 1.f) * 31.5f;
        int bi = blockIdx.x;
        int b = bi >> 12, p = bi & 4095;
        flow_out[(long long)b * 8192 + p]        = mx - (float)(p & 63);
        flow_out[(long long)b * 8192 + 4096 + p] = my - (float)(p >> 6);
    }
}

// ---------------------------------------------------------------------------
// Output layout (floats): trans_features @0 (2,097,152) | coarse @2,097,152
// (2,097,152) | c @4,194,304 (33,554,432) | c_flip @37,748,736 (33,554,432)
// | flow @71,303,168 (16,384) | flow_flip @71,319,552 (16,384)
// ---------------------------------------------------------------------------
extern "C" void kernel_launch(void* const* d_in, const int* in_sizes, int n_in,
                              void* d_out, int out_size, void* d_ws, size_t ws_size,
                              hipStream_t stream) {
    const float* f0c = (const float*)d_in[0];
    const float* f1c = (const float*)d_in[1];
    const float* f0f = (const float*)d_in[2];
    const float* f1f = (const float*)d_in[3];
    float* out = (float*)d_out;

    float* corr_ws = out;                    // reuse trans_features region (exactly 2,097,152 floats) as scratch
    float* c_out   = out + 4194304;
    float* cf_out  = out + 37748736;
    float* flow    = out + 71303168;
    float* flowf   = out + 71319552;

    k_corr_c<<<dim3(16, 16, 2), 256, 0, stream>>>(f0c, f1c, corr_ws);
    k_fused<<<dim3(64, 64, 2), 256, 0, stream>>>(f0f, f1f, corr_ws, c_out, cf_out);
    // corr_ws consumed; now write the real trans_features over it
    k_copy_trans<<<2048, 256, 0, stream>>>(f0f, f1f, out);
    k_coarse<<<8192, 256, 0, stream>>>(f0c, f1c, out + 2097152);
    k_softargmax<<<8192, 256, 0, stream>>>(c_out, flow);
    k_softargmax<<<8192, 256, 0, stream>>>(cf_out, flowf);
}

// Round 2
// 456.361 us; speedup vs baseline: 1.0830x; 1.0830x over previous
//
#include <hip/hip_runtime.h>
#include <math.h>

#define SCALE_C 0.08838834764831845f  // 1/sqrt(128)
#define INV_BETA 50.0f
#define STEP63 (2.0f / 63.0f)

// align_corners bilinear coefficients for 32 -> 64 (src = t*31/63)
__device__ __forceinline__ void interp_coef32(int t, int& i0, int& i1, float& w) {
    float s = (float)(t * 31) / 63.0f;
    i0 = (int)floorf(s);
    if (i0 > 31) i0 = 31;
    i1 = i0 + 1;
    if (i1 > 31) i1 = 31;
    w = s - (float)i0;
}

// ---------------------------------------------------------------------------
// corr_c: [b,1024,1024] = f0c^T f1c / sqrt(128). 64x64 tile per block.
// ---------------------------------------------------------------------------
__global__ __launch_bounds__(256) void k_corr_c(const float* __restrict__ f0c,
                                                const float* __restrict__ f1c,
                                                float* __restrict__ ws) {
    __shared__ float As[16][64];
    __shared__ float Bs[16][64];
    const int b = blockIdx.z;
    const int m0 = blockIdx.y * 64, n0 = blockIdx.x * 64;
    const float* A  = f0c + (long long)b * 131072;
    const float* Bp = f1c + (long long)b * 131072;
    const int tid = threadIdx.x;
    const int tx = tid & 15, ty = tid >> 4;
    const int lk = tid >> 4;
    const int lc = (tid & 15) * 4;
    float acc[4][4] = {{0.f}};
    for (int k0 = 0; k0 < 128; k0 += 16) {
        *(float4*)&As[lk][lc] = *(const float4*)&A[(k0 + lk) * 1024 + m0 + lc];
        *(float4*)&Bs[lk][lc] = *(const float4*)&Bp[(k0 + lk) * 1024 + n0 + lc];
        __syncthreads();
#pragma unroll
        for (int kk = 0; kk < 16; ++kk) {
            float4 a4 = *(float4*)&As[kk][ty * 4];
            float4 b4 = *(float4*)&Bs[kk][tx * 4];
            float av[4] = {a4.x, a4.y, a4.z, a4.w};
            float bv[4] = {b4.x, b4.y, b4.z, b4.w};
#pragma unroll
            for (int i = 0; i < 4; ++i)
#pragma unroll
                for (int j = 0; j < 4; ++j)
                    acc[i][j] = fmaf(av[i], bv[j], acc[i][j]);
        }
        __syncthreads();
    }
#pragma unroll
    for (int i = 0; i < 4; ++i) {
        float4 w4 = make_float4(acc[i][0] * SCALE_C, acc[i][1] * SCALE_C,
                                acc[i][2] * SCALE_C, acc[i][3] * SCALE_C);
        *(float4*)&ws[(long long)b * 1048576 + (long long)(m0 + ty * 4 + i) * 1024 + n0 + tx * 4] = w4;
    }
}

// ---------------------------------------------------------------------------
// k_fused2: 128x128 tile of the 4096x4096 fp32 GEMM (K=128), 8x8 micro-tile.
// Adds upsampled coarse corr, writes c + c_flip, and emits online-softmax
// partials for both flow directions into `parts`.
// parts layout (float4): dir0 [b][p0][32 colblk] at 0, dir1 [b][p1][32 rowblk]
// at float4 offset 262144.
// ---------------------------------------------------------------------------
__global__ __launch_bounds__(256, 3) void k_fused2(const float* __restrict__ f0f,
                                                   const float* __restrict__ f1f,
                                                   const float* __restrict__ cws,
                                                   float* __restrict__ c_out,
                                                   float* __restrict__ cf_out,
                                                   float* __restrict__ parts) {
    // smem: As [16][128] @0 (2048) | Bs [16][128] @2048 (2048) | tmp2 [4][32][68] @4096 (8704)
    __shared__ __attribute__((aligned(16))) float smem[12800];
    const int TMP2 = 4096;
    const int b = blockIdx.z, by = blockIdx.y, bx = blockIdx.x;
    const int tid = threadIdx.x;
    const int wv = tid >> 6;
    const int tcl = tid & 7;
    const int trl = (tid >> 3) & 7;
    const int tc = tcl + (wv & 1) * 8;   // 0..15
    const int tr = trl + (wv >> 1) * 8;  // 0..15

    // ---- build tmp2: y0/y1-interpolated + x1-interpolated coarse corr ----
    {
        const float* Cc = cws + (long long)b * 1048576;
        for (int e = tid; e < 8192; e += 256) {
            int pair = e >> 11, rem = e & 2047;
            int xc0 = rem >> 6, x1 = rem & 63;
            int s0 = pair >> 1, s1 = pair & 1;
            int ya, yb; float wy0; interp_coef32(2 * by + s0, ya, yb, wy0);
            int za, zb; float wy1; interp_coef32(2 * bx + s1, za, zb, wy1);
            int xa, xb; float wx1; interp_coef32(x1, xa, xb, wx1);
            const float* r0 = Cc + (long long)(ya * 32 + xc0) * 1024;
            const float* r1 = Cc + (long long)(yb * 32 + xc0) * 1024;
            float g0 = (r0[za * 32 + xa] * (1.f - wy1) + r0[zb * 32 + xa] * wy1) * (1.f - wy0)
                     + (r1[za * 32 + xa] * (1.f - wy1) + r1[zb * 32 + xa] * wy1) * wy0;
            float g1 = (r0[za * 32 + xb] * (1.f - wy1) + r0[zb * 32 + xb] * wy1) * (1.f - wy0)
                     + (r1[za * 32 + xb] * (1.f - wy1) + r1[zb * 32 + xb] * wy1) * wy0;
            smem[TMP2 + (pair * 32 + xc0) * 68 + x1] = g0 * (1.f - wx1) + g1 * wx1;
        }
    }

    // ---- GEMM: acc[8][8] over K=128 ----
    const float* Ag = f0f + (long long)b * 524288 + by * 128;
    const float* Bg = f1f + (long long)b * 524288 + bx * 128;
    float acc[8][8];
#pragma unroll
    for (int i = 0; i < 8; ++i)
#pragma unroll
        for (int j = 0; j < 8; ++j) acc[i][j] = 0.f;

    for (int ks = 0; ks < 8; ++ks) {
        __syncthreads();
        {
            int v0 = tid, v1 = tid + 256;
            *(float4*)&smem[(v0 >> 5) * 128 + (v0 & 31) * 4] =
                *(const float4*)&Ag[(long long)(ks * 16 + (v0 >> 5)) * 4096 + (v0 & 31) * 4];
            *(float4*)&smem[(v1 >> 5) * 128 + (v1 & 31) * 4] =
                *(const float4*)&Ag[(long long)(ks * 16 + (v1 >> 5)) * 4096 + (v1 & 31) * 4];
            *(float4*)&smem[2048 + (v0 >> 5) * 128 + (v0 & 31) * 4] =
                *(const float4*)&Bg[(long long)(ks * 16 + (v0 >> 5)) * 4096 + (v0 & 31) * 4];
            *(float4*)&smem[2048 + (v1 >> 5) * 128 + (v1 & 31) * 4] =
                *(const float4*)&Bg[(long long)(ks * 16 + (v1 >> 5)) * 4096 + (v1 & 31) * 4];
        }
        __syncthreads();
#pragma unroll
        for (int kk = 0; kk < 16; ++kk) {
            float4 a0 = *(float4*)&smem[kk * 128 + tr * 8];
            float4 a1 = *(float4*)&smem[kk * 128 + tr * 8 + 4];
            float4 b0 = *(float4*)&smem[2048 + kk * 128 + tc * 8];
            float4 b1 = *(float4*)&smem[2048 + kk * 128 + tc * 8 + 4];
            float av[8] = {a0.x, a0.y, a0.z, a0.w, a1.x, a1.y, a1.z, a1.w};
            float bv[8] = {b0.x, b0.y, b0.z, b0.w, b1.x, b1.y, b1.z, b1.w};
#pragma unroll
            for (int i = 0; i < 8; ++i)
#pragma unroll
                for (int j = 0; j < 8; ++j)
                    acc[i][j] = fmaf(av[i], bv[j], acc[i][j]);
        }
    }

    // ---- epilogue: upsample + combine ----
    const int pair = wv;                    // == (tr>>3)*2 + (tc>>3)
    const int x0b = (tr & 7) * 8, x1b = (tc & 7) * 8;
#pragma unroll
    for (int i = 0; i < 8; ++i) {
        int i0, i1; float w0; interp_coef32(x0b + i, i0, i1, w0);
        float4 ua0 = *(float4*)&smem[TMP2 + (pair * 32 + i0) * 68 + x1b];
        float4 ua1 = *(float4*)&smem[TMP2 + (pair * 32 + i0) * 68 + x1b + 4];
        float4 ub0 = *(float4*)&smem[TMP2 + (pair * 32 + i1) * 68 + x1b];
        float4 ub1 = *(float4*)&smem[TMP2 + (pair * 32 + i1) * 68 + x1b + 4];
        float up[8] = {ua0.x * (1.f - w0) + ub0.x * w0, ua0.y * (1.f - w0) + ub0.y * w0,
                       ua0.z * (1.f - w0) + ub0.z * w0, ua0.w * (1.f - w0) + ub0.w * w0,
                       ua1.x * (1.f - w0) + ub1.x * w0, ua1.y * (1.f - w0) + ub1.y * w0,
                       ua1.z * (1.f - w0) + ub1.z * w0, ua1.w * (1.f - w0) + ub1.w * w0};
#pragma unroll
        for (int j = 0; j < 8; ++j)
            acc[i][j] = (acc[i][j] * SCALE_C + up[j]) * 0.5f;
    }

    // ---- stores: c (row-major) and c_flip (transposed, i-contiguous f4) ----
    {
        long long cb = ((long long)b << 24) + (long long)(by * 128 + tr * 8) * 4096 + bx * 128 + tc * 8;
#pragma unroll
        for (int i = 0; i < 8; ++i) {
            *(float4*)&c_out[cb + (long long)i * 4096] =
                make_float4(acc[i][0], acc[i][1], acc[i][2], acc[i][3]);
            *(float4*)&c_out[cb + (long long)i * 4096 + 4] =
                make_float4(acc[i][4], acc[i][5], acc[i][6], acc[i][7]);
        }
        long long fb = ((long long)b << 24) + (long long)(bx * 128 + tc * 8) * 4096 + by * 128 + tr * 8;
#pragma unroll
        for (int j = 0; j < 8; ++j) {
            *(float4*)&cf_out[fb + (long long)j * 4096] =
                make_float4(acc[0][j], acc[1][j], acc[2][j], acc[3][j]);
            *(float4*)&cf_out[fb + (long long)j * 4096 + 4] =
                make_float4(acc[4][j], acc[5][j], acc[6][j], acc[7][j]);
        }
    }

    // ---- softmax partials ----
    float4* pred4 = (float4*)smem;          // reuse As/Bs region (GEMM done)
    float4* parts4 = (float4*)parts;
    __syncthreads();                        // ensure all waves done reading As/Bs

    // c-direction: rows p0 = by*128 + tr*8 + i, reduce over block cols
    {
        float yn1 = -1.f + (float)(2 * bx + (tc >> 3)) * STEP63;  // source y1 (thread-const)
#pragma unroll
        for (int i = 0; i < 8; ++i) {
            float m = acc[i][0];
#pragma unroll
            for (int j = 1; j < 8; ++j) m = fmaxf(m, acc[i][j]);
            m = fmaxf(m, __shfl_xor(m, 1, 64));
            m = fmaxf(m, __shfl_xor(m, 2, 64));
            m = fmaxf(m, __shfl_xor(m, 4, 64));
            float l = 0.f, sx = 0.f;
#pragma unroll
            for (int j = 0; j < 8; ++j) {
                float e = __expf((acc[i][j] - m) * INV_BETA);
                l += e;
                sx += e * (-1.f + (float)(x1b + j) * STEP63);
            }
            l += __shfl_xor(l, 1, 64);  sx += __shfl_xor(sx, 1, 64);
            l += __shfl_xor(l, 2, 64);  sx += __shfl_xor(sx, 2, 64);
            l += __shfl_xor(l, 4, 64);  sx += __shfl_xor(sx, 4, 64);
            if (tcl == 0) pred4[(wv & 1) * 128 + tr * 8 + i] = make_float4(m, l, sx, yn1 * l);
        }
    }
    __syncthreads();
    if (tid < 128) {
        float4 h0 = pred4[tid], h1 = pred4[128 + tid];
        float M = fmaxf(h0.x, h1.x);
        float s0 = __expf((h0.x - M) * INV_BETA);
        float s1 = __expf((h1.x - M) * INV_BETA);
        parts4[((long long)b * 4096 + by * 128 + tid) * 32 + bx] =
            make_float4(M, h0.y * s0 + h1.y * s1, h0.z * s0 + h1.z * s1, h0.w * s0 + h1.w * s1);
    }
    __syncthreads();

    // f-direction: rows p1 = bx*128 + tc*8 + j, reduce over block rows
    {
        float yn0 = -1.f + (float)(2 * by + (tr >> 3)) * STEP63;  // source y0 (thread-const)
#pragma unroll
        for (int j = 0; j < 8; ++j) {
            float m = acc[0][j];
#pragma unroll
            for (int i = 1; i < 8; ++i) m = fmaxf(m, acc[i][j]);
            m = fmaxf(m, __shfl_xor(m, 8, 64));
            m = fmaxf(m, __shfl_xor(m, 16, 64));
            m = fmaxf(m, __shfl_xor(m, 32, 64));
            float l = 0.f, sx = 0.f;
#pragma unroll
            for (int i = 0; i < 8; ++i) {
                float e = __expf((acc[i][j] - m) * INV_BETA);
                l += e;
                sx += e * (-1.f + (float)(x0b + i) * STEP63);
            }
            l += __shfl_xor(l, 8, 64);   sx += __shfl_xor(sx, 8, 64);
            l += __shfl_xor(l, 16, 64);  sx += __shfl_xor(sx, 16, 64);
            l += __shfl_xor(l, 32, 64);  sx += __shfl_xor(sx, 32, 64);
            if (trl == 0) pred4[(wv >> 1) * 128 + tc * 8 + j] = make_float4(m, l, sx, yn0 * l);
        }
    }
    __syncthreads();
    if (tid < 128) {
        float4 h0 = pred4[tid], h1 = pred4[128 + tid];
        float M = fmaxf(h0.x, h1.x);
        float s0 = __expf((h0.x - M) * INV_BETA);
        float s1 = __expf((h1.x - M) * INV_BETA);
        parts4[262144 + ((long long)b * 4096 + bx * 128 + tid) * 32 + by] =
            make_float4(M, h0.y * s0 + h1.y * s1, h0.z * s0 + h1.z * s1, h0.w * s0 + h1.w * s1);
    }
}

// ---------------------------------------------------------------------------
// k_flow: merge 32 partials per row -> flow values. One wave per row.
// rows: dir*8192 + b*4096 + p ; 16384 rows total.
// ---------------------------------------------------------------------------
__global__ __launch_bounds__(256) void k_flow(const float* __restrict__ parts,
                                              float* __restrict__ flow,
                                              float* __restrict__ flowf) {
    const int row = blockIdx.x * 4 + (threadIdx.x >> 6);
    const int lane = threadIdx.x & 63;
    const float4* p4 = (const float4*)parts + (long long)row * 32;
    float m = -1e30f, l = 0.f, sx = 0.f, sy = 0.f;
    if (lane < 32) { float4 v = p4[lane]; m = v.x; l = v.y; sx = v.z; sy = v.w; }
    float M = m;
#pragma unroll
    for (int off = 1; off < 64; off <<= 1) M = fmaxf(M, __shfl_xor(M, off, 64));
    float s = __expf((m - M) * INV_BETA);
    l *= s; sx *= s; sy *= s;
#pragma unroll
    for (int off = 1; off < 64; off <<= 1) {
        l += __shfl_xor(l, off, 64);
        sx += __shfl_xor(sx, off, 64);
        sy += __shfl_xor(sy, off, 64);
    }
    if (lane == 0) {
        float gx = sx / l, gy = sy / l;
        float mx = (gx + 1.f) * 31.5f, my = (gy + 1.f) * 31.5f;
        int dir = row >> 13, b = (row >> 12) & 1, p = row & 4095;
        float* o = dir ? flowf : flow;
        o[(long long)b * 8192 + p] = mx - (float)(p & 63);
        o[(long long)b * 8192 + 4096 + p] = my - (float)(p >> 6);
    }
}

// ---------------------------------------------------------------------------
// trans_features = stack([f0f, f1f], axis=1)
// ---------------------------------------------------------------------------
__global__ void k_copy_trans(const float* __restrict__ f0f, const float* __restrict__ f1f,
                             float* __restrict__ out1) {
    int idx = blockIdx.x * 256 + threadIdx.x;
    int bv = idx >> 17;
    int r = idx & 131071;
    int b = bv >> 1, v = bv & 1;
    const float4* src = (const float4*)(v ? f1f : f0f) + (long long)b * 131072 + r;
    ((float4*)out1)[idx] = *src;
}

// ---------------------------------------------------------------------------
// trans_features_coarse: bilinear 32->64 of stacked feat_c
// ---------------------------------------------------------------------------
__global__ void k_coarse(const float* __restrict__ f0c, const float* __restrict__ f1c,
                         float* __restrict__ out2) {
    int idx = blockIdx.x * 256 + threadIdx.x;
    int x = idx & 63, y = (idx >> 6) & 63, ch = (idx >> 12) & 127;
    int v = (idx >> 19) & 1, b = idx >> 20;
    int iy0, iy1; float wy; interp_coef32(y, iy0, iy1, wy);
    int ix0, ix1; float wx; interp_coef32(x, ix0, ix1, wx);
    const float* src = (v ? f1c : f0c) + (long long)(b * 128 + ch) * 1024;
    float a  = src[iy0 * 32 + ix0] * (1.f - wy) + src[iy1 * 32 + ix0] * wy;
    float c2 = src[iy0 * 32 + ix1] * (1.f - wy) + src[iy1 * 32 + ix1] * wy;
    out2[idx] = a * (1.f - wx) + c2 * wx;
}

// ========================= fallback path (round-1) =========================
__global__ __launch_bounds__(256) void k_fused_fb(const float* __restrict__ f0f,
                                                  const float* __restrict__ f1f,
                                                  const float* __restrict__ cws,
                                                  float* __restrict__ c_out,
                                                  float* __restrict__ cf_out) {
    __shared__ float As[16][64];
    __shared__ float Bs[16][64];
    __shared__ float tmp[32][33];
    const int b = blockIdx.z, y0 = blockIdx.y, y1 = blockIdx.x;
    const int tid = threadIdx.x;
    const int tx = tid & 15, ty = tid >> 4;
    const float* A  = f0f + (long long)b * 524288 + y0 * 64;
    const float* Bp = f1f + (long long)b * 524288 + y1 * 64;
    int iy0a, iy0b; float wy0; interp_coef32(y0, iy0a, iy0b, wy0);
    int iy1a, iy1b; float wy1; interp_coef32(y1, iy1a, iy1b, wy1);
    const float* Cc = cws + (long long)b * 1048576;
    for (int r = tid; r < 1024; r += 256) {
        int i = r >> 5, j = r & 31;
        const float* ra = Cc + (long long)(iy0a * 32 + i) * 1024;
        const float* rb = Cc + (long long)(iy0b * 32 + i) * 1024;
        float va = ra[iy1a * 32 + j] * (1.f - wy1) + ra[iy1b * 32 + j] * wy1;
        float vb = rb[iy1a * 32 + j] * (1.f - wy1) + rb[iy1b * 32 + j] * wy1;
        tmp[i][j] = va * (1.f - wy0) + vb * wy0;
    }
    float acc[4][4] = {{0.f}};
    const int lk = tid >> 4;
    const int lc = (tid & 15) * 4;
    for (int k0 = 0; k0 < 128; k0 += 16) {
        *(float4*)&As[lk][lc] = *(const float4*)&A[(long long)(k0 + lk) * 4096 + lc];
        *(float4*)&Bs[lk][lc] = *(const float4*)&Bp[(long long)(k0 + lk) * 4096 + lc];
        __syncthreads();
#pragma unroll
        for (int kk = 0; kk < 16; ++kk) {
            float4 a4 = *(float4*)&As[kk][ty * 4];
            float4 b4 = *(float4*)&Bs[kk][tx * 4];
            float av[4] = {a4.x, a4.y, a4.z, a4.w};
            float bv[4] = {b4.x, b4.y, b4.z, b4.w};
#pragma unroll
            for (int i = 0; i < 4; ++i)
#pragma unroll
                for (int j = 0; j < 4; ++j)
                    acc[i][j] = fmaf(av[i], bv[j], acc[i][j]);
        }
        __syncthreads();
    }
    int ix0a[4], ix0b[4]; float wx0[4];
    int ix1a[4], ix1b[4]; float wx1[4];
#pragma unroll
    for (int i = 0; i < 4; ++i) interp_coef32(ty * 4 + i, ix0a[i], ix0b[i], wx0[i]);
#pragma unroll
    for (int j = 0; j < 4; ++j) interp_coef32(tx * 4 + j, ix1a[j], ix1b[j], wx1[j]);
    float val[4][4];
#pragma unroll
    for (int i = 0; i < 4; ++i)
#pragma unroll
        for (int j = 0; j < 4; ++j) {
            float ta = tmp[ix0a[i]][ix1a[j]] * (1.f - wx1[j]) + tmp[ix0a[i]][ix1b[j]] * wx1[j];
            float tb = tmp[ix0b[i]][ix1a[j]] * (1.f - wx1[j]) + tmp[ix0b[i]][ix1b[j]] * wx1[j];
            val[i][j] = (acc[i][j] * SCALE_C + (ta * (1.f - wx0[i]) + tb * wx0[i])) * 0.5f;
        }
    const long long cbase = ((long long)b << 24) + (long long)(y0 * 64) * 4096 + y1 * 64;
#pragma unroll
    for (int i = 0; i < 4; ++i)
        *(float4*)&c_out[cbase + (long long)(ty * 4 + i) * 4096 + tx * 4] =
            make_float4(val[i][0], val[i][1], val[i][2], val[i][3]);
    const long long fbase = ((long long)b << 24) + (long long)(y1 * 64) * 4096 + y0 * 64;
#pragma unroll
    for (int j = 0; j < 4; ++j)
        *(float4*)&cf_out[fbase + (long long)(tx * 4 + j) * 4096 + ty * 4] =
            make_float4(val[0][j], val[1][j], val[2][j], val[3][j]);
}

__global__ __launch_bounds__(256) void k_softargmax(const float* __restrict__ cmat,
                                                    float* __restrict__ flow_out) {
    const int tid = threadIdx.x;
    const float4* src = (const float4*)cmat + (long long)blockIdx.x * 1024;
    float4 r0 = src[tid];
    float4 r1 = src[tid + 256];
    float4 r2 = src[tid + 512];
    float4 r3 = src[tid + 768];
    float m = fmaxf(fmaxf(fmaxf(r0.x, r0.y), fmaxf(r0.z, r0.w)),
                    fmaxf(fmaxf(r1.x, r1.y), fmaxf(r1.z, r1.w)));
    m = fmaxf(m, fmaxf(fmaxf(r2.x, r2.y), fmaxf(r2.z, r2.w)));
    m = fmaxf(m, fmaxf(fmaxf(r3.x, r3.y), fmaxf(r3.z, r3.w)));
    __shared__ float red[16];
    const int lane = tid & 63, wave = tid >> 6;
#pragma unroll
    for (int off = 32; off > 0; off >>= 1) m = fmaxf(m, __shfl_xor(m, off, 64));
    if (lane == 0) red[wave] = m;
    __syncthreads();
    m = fmaxf(fmaxf(red[0], red[1]), fmaxf(red[2], red[3]));
    float l = 0.f, sx = 0.f, sy = 0.f;
#pragma unroll
    for (int s = 0; s < 4; ++s) {
        float4 r = (s == 0) ? r0 : (s == 1) ? r1 : (s == 2) ? r2 : r3;
        int f = tid + s * 256;
        float yn = -1.f + (float)(f >> 4) * STEP63;
        float xb = (float)((f & 15) * 4);
        float e0 = __expf((r.x - m) * 50.f);
        float e1 = __expf((r.y - m) * 50.f);
        float e2 = __expf((r.z - m) * 50.f);
        float e3 = __expf((r.w - m) * 50.f);
        float es = e0 + e1 + e2 + e3;
        l += es;
        sy += es * yn;
        sx += e0 * (-1.f + xb * STEP63) + e1 * (-1.f + (xb + 1.f) * STEP63)
            + e2 * (-1.f + (xb + 2.f) * STEP63) + e3 * (-1.f + (xb + 3.f) * STEP63);
    }
#pragma unroll
    for (int off = 32; off > 0; off >>= 1) {
        l  += __shfl_xor(l, off, 64);
        sx += __shfl_xor(sx, off, 64);
        sy += __shfl_xor(sy, off, 64);
    }
    if (lane == 0) { red[4 + wave] = l; red[8 + wave] = sx; red[12 + wave] = sy; }
    __syncthreads();
    if (tid == 0) {
        float L  = red[4] + red[5] + red[6] + red[7];
        float SX = red[8] + red[9] + red[10] + red[11];
        float SY = red[12] + red[13] + red[14] + red[15];
        float mx = (SX / L + 1.f) * 31.5f;
        float my = (SY / L + 1.f) * 31.5f;
        int bi = blockIdx.x;
        int b = bi >> 12, p = bi & 4095;
        flow_out[(long long)b * 8192 + p]        = mx - (float)(p & 63);
        flow_out[(long long)b * 8192 + 4096 + p] = my - (float)(p >> 6);
    }
}

// ---------------------------------------------------------------------------
// Output layout (floats): trans_features @0 | coarse @2,097,152 | c @4,194,304
// | c_flip @37,748,736 | flow @71,303,168 | flow_flip @71,319,552
// ---------------------------------------------------------------------------
extern "C" void kernel_launch(void* const* d_in, const int* in_sizes, int n_in,
                              void* d_out, int out_size, void* d_ws, size_t ws_size,
                              hipStream_t stream) {
    const float* f0c = (const float*)d_in[0];
    const float* f1c = (const float*)d_in[1];
    const float* f0f = (const float*)d_in[2];
    const float* f1f = (const float*)d_in[3];
    float* out = (float*)d_out;

    float* c_out  = out + 4194304;
    float* cf_out = out + 37748736;
    float* flow   = out + 71303168;
    float* flowf  = out + 71319552;

    if (ws_size >= (size_t)16777216) {
        float* parts = (float*)d_ws;          // 2,097,152 floats (8 MB): softmax partials
        float* cws   = parts + 2097152;       // 2,097,152 floats (8 MB): coarse corr
        k_corr_c<<<dim3(16, 16, 2), 256, 0, stream>>>(f0c, f1c, cws);
        k_fused2<<<dim3(32, 32, 2), 256, 0, stream>>>(f0f, f1f, cws, c_out, cf_out, parts);
        k_flow<<<4096, 256, 0, stream>>>(parts, flow, flowf);
        k_copy_trans<<<2048, 256, 0, stream>>>(f0f, f1f, out);
        k_coarse<<<8192, 256, 0, stream>>>(f0c, f1c, out + 2097152);
    } else {
        float* corr_ws = out;                 // reuse trans_features region as scratch
        k_corr_c<<<dim3(16, 16, 2), 256, 0, stream>>>(f0c, f1c, corr_ws);
        k_fused_fb<<<dim3(64, 64, 2), 256, 0, stream>>>(f0f, f1f, corr_ws, c_out, cf_out);
        k_copy_trans<<<2048, 256, 0, stream>>>(f0f, f1f, out);
        k_coarse<<<8192, 256, 0, stream>>>(f0c, f1c, out + 2097152);
        k_softargmax<<<8192, 256, 0, stream>>>(c_out, flow);
        k_softargmax<<<8192, 256, 0, stream>>>(cf_out, flowf);
    }
}